// Round 8
// baseline (465.900 us; speedup 1.0000x reference)
//
#include <hip/hip_runtime.h>

#define DD 128
#define NHEAD 8
#define DH 16
#define EPS 1e-5f
#define BSH 9                 // bucket width 512 nodes
#define BWIDTH 512
#define NBLK1 256             // pass-1 blocks
#define QPAD 33               // padded row length: 132 % 32 = 4 -> 4-way max on transpose writes

// ---------- bf16 helpers (OCP bf16 = f32 upper half, RNE) ----------
__device__ inline unsigned short f2b(float f) {
    unsigned u = __float_as_uint(f);
    u += 0x7fffu + ((u >> 16) & 1);
    return (unsigned short)(u >> 16);
}
__device__ inline unsigned pk2(float lo, float hi) {
    return (unsigned)f2b(lo) | ((unsigned)f2b(hi) << 16);
}

// ================= h -> bf16 copy =================
__global__ void k_h2b(const float4* __restrict__ h4, ushort4* __restrict__ hb, int n4) {
    int i = blockIdx.x * 256 + threadIdx.x;
    if (i < n4) {
        float4 v = h4[i];
        hb[i] = make_ushort4(f2b(v.x), f2b(v.y), f2b(v.z), f2b(v.w));
    }
}

// ================= pass 1a: per-block bucket histograms =================
__global__ __launch_bounds__(256) void k_p1count(
        const int* __restrict__ gs, const int* __restrict__ gd,
        const int* __restrict__ as_, const int* __restrict__ ad,
        int* __restrict__ blkcnt, int E, int N, int Btot) {
    __shared__ int cnts[512];
    for (int j = threadIdx.x; j < 2 * Btot; j += 256) cnts[j] = 0;
    __syncthreads();
    int E2 = 2 * E;
    for (int i = blockIdx.x * 256 + threadIdx.x; i < E2; i += NBLK1 * 256) {
        int g = (i >= E);
        int e = g ? i - E : i;
        int s = g ? as_[e] : gs[e];
        int d = g ? ad[e] : gd[e];
        int cd = d + g * N, cs = s + g * N;
        atomicAdd(&cnts[cd >> BSH], 1);
        atomicAdd(&cnts[Btot + (cs >> BSH)], 1);
    }
    __syncthreads();
    for (int j = threadIdx.x; j < 2 * Btot; j += 256)
        blkcnt[j * NBLK1 + blockIdx.x] = cnts[j];
}

// ================= 3-stage scan =================
__global__ void k_scan1(const int* __restrict__ cnt, int* __restrict__ outv,
                        int* __restrict__ part, int n) {
    __shared__ int wsums[4];
    int t = threadIdx.x;
    int base = blockIdx.x * 1024 + t * 4;
    int v0 = 0, v1 = 0, v2 = 0, v3 = 0;
    if (base + 3 < n) {
        int4 q = *(const int4*)(cnt + base);
        v0 = q.x; v1 = q.y; v2 = q.z; v3 = q.w;
    } else {
        if (base < n)     v0 = cnt[base];
        if (base + 1 < n) v1 = cnt[base + 1];
        if (base + 2 < n) v2 = cnt[base + 2];
        if (base + 3 < n) v3 = cnt[base + 3];
    }
    int s0 = v0, s1 = s0 + v1, s2 = s1 + v2, s3 = s2 + v3;
    int x = s3;
    int lane = t & 63, w = t >> 6;
    for (int o = 1; o < 64; o <<= 1) { int u = __shfl_up(x, o); if (lane >= o) x += u; }
    if (lane == 63) wsums[w] = x;
    __syncthreads();
    int wo = 0;
    for (int i = 0; i < w; ++i) wo += wsums[i];
    int excl = wo + x - s3;
    if (base < n)     outv[base]     = excl;
    if (base + 1 < n) outv[base + 1] = excl + s0;
    if (base + 2 < n) outv[base + 2] = excl + s1;
    if (base + 3 < n) outv[base + 3] = excl + s2;
    if (t == 255) part[blockIdx.x] = wo + x;
}

__global__ void k_scan2(int* __restrict__ part, int nb) {
    __shared__ int ws[4];
    int t = threadIdx.x;
    int v = (t < nb) ? part[t] : 0;
    int x = v;
    int lane = t & 63, w = t >> 6;
    for (int o = 1; o < 64; o <<= 1) { int u = __shfl_up(x, o); if (lane >= o) x += u; }
    if (lane == 63) ws[w] = x;
    __syncthreads();
    int wo = 0;
    for (int i = 0; i < w; ++i) wo += ws[i];
    if (t < nb) part[t] = wo + x - v;
}

__global__ void k_scan3(int* __restrict__ outv, const int* __restrict__ part, int n, int total) {
    int i = blockIdx.x * blockDim.x + threadIdx.x;
    if (i < n) outv[i] += part[i >> 10];
    if (i == 0) outv[n] = total;
}

// ================= pass 1b: scatter edges into bucket regions =================
__global__ __launch_bounds__(256) void k_p1scatter(
        const int* __restrict__ gs, const int* __restrict__ gd,
        const int* __restrict__ as_, const int* __restrict__ ad,
        const int* __restrict__ scn, int2* __restrict__ pairs, int* __restrict__ svals,
        int E, int N, int Btot) {
    __shared__ int cur[512];
    for (int j = threadIdx.x; j < 2 * Btot; j += 256)
        cur[j] = scn[j * NBLK1 + blockIdx.x];
    __syncthreads();
    int E2 = 2 * E;
    for (int i = blockIdx.x * 256 + threadIdx.x; i < E2; i += NBLK1 * 256) {
        int g = (i >= E);
        int e = g ? i - E : i;
        int s = g ? as_[e] : gs[e];
        int d = g ? ad[e] : gd[e];
        int cd = d + g * N, cs = s + g * N;
        int pd = atomicAdd(&cur[cd >> BSH], 1);
        pairs[pd] = make_int2(cd, s);
        int ps = atomicAdd(&cur[Btot + (cs >> BSH)], 1);
        svals[ps - E2] = cs;
    }
}

// ================= pass 2: per-bucket CSR + indeg + norms =================
__global__ __launch_bounds__(256) void k_p2(
        const int2* __restrict__ pairs, const int* __restrict__ svals,
        const int* __restrict__ scn, int* __restrict__ rowptr, int* __restrict__ csr,
        float* __restrict__ indeg, float* __restrict__ norms,
        int E, int N2, int Btot) {
    __shared__ int hist[BWIDTH];
    __shared__ int offs[BWIDTH];
    __shared__ int cur[BWIDTH];
    __shared__ int ws4[4];
    int b = blockIdx.x, t = threadIdx.x;
    int node0 = b << BSH;
    int W = N2 - node0; if (W > BWIDTH) W = BWIDTH;
    int Sd = scn[b * NBLK1], Ed = scn[(b + 1) * NBLK1];
    hist[t] = 0; hist[t + 256] = 0;
    __syncthreads();
    for (int i = Sd + t; i < Ed; i += 256) {
        int2 p = pairs[i];
        atomicAdd(&hist[p.x - node0], 1);
    }
    __syncthreads();
    int a0 = hist[2 * t], a1 = hist[2 * t + 1];
    int sum2 = a0 + a1;
    int lane = t & 63, w = t >> 6;
    int x = sum2;
    for (int o = 1; o < 64; o <<= 1) { int u = __shfl_up(x, o); if (lane >= o) x += u; }
    if (lane == 63) ws4[w] = x;
    __syncthreads();
    int wo = 0;
    for (int i = 0; i < w; ++i) wo += ws4[i];
    int excl2 = wo + x - sum2;
    offs[2 * t] = excl2; offs[2 * t + 1] = excl2 + a0;
    cur[t] = 0; cur[t + 256] = 0;
    __syncthreads();
    for (int j = t; j < W; j += 256) {
        rowptr[node0 + j] = Sd + offs[j];
        indeg[node0 + j] = (float)hist[j];
    }
    if (b == 0 && t == 0) rowptr[N2] = 2 * E;
    for (int i = Sd + t; i < Ed; i += 256) {
        int2 p = pairs[i];
        int l = p.x - node0;
        int pos = atomicAdd(&cur[l], 1);
        csr[Sd + offs[l] + pos] = p.y;
    }
    __syncthreads();
    hist[t] = 0; hist[t + 256] = 0;
    __syncthreads();
    int Ss = scn[(Btot + b) * NBLK1] - 2 * E;
    int Es = scn[(Btot + b + 1) * NBLK1] - 2 * E;
    for (int i = Ss + t; i < Es; i += 256)
        atomicAdd(&hist[svals[i] - node0], 1);
    __syncthreads();
    for (int j = t; j < W; j += 256) {
        int od = hist[j];
        norms[node0 + j] = od > 0 ? rsqrtf((float)od) : 0.f;
    }
}

// ---------- 8-wide bf16 accumulate from uint4 ----------
__device__ inline void acc8(uint4 v, float* a) {
    a[0] += __uint_as_float(v.x << 16);
    a[1] += __uint_as_float(v.x & 0xffff0000u);
    a[2] += __uint_as_float(v.y << 16);
    a[3] += __uint_as_float(v.y & 0xffff0000u);
    a[4] += __uint_as_float(v.z << 16);
    a[5] += __uint_as_float(v.z & 0xffff0000u);
    a[6] += __uint_as_float(v.w << 16);
    a[7] += __uint_as_float(v.w & 0xffff0000u);
}

// ================= pull: avg (SAGE); 16 lanes/node, uint4 (16B) per lane =================
__global__ __launch_bounds__(256) void k_pull_avg(
        const uint4* __restrict__ xb, const int* __restrict__ rowptr,
        const int* __restrict__ csr, const float* __restrict__ norm_s,
        uint4* __restrict__ outb, int N, int doscale) {
    int node = blockIdx.x * 16 + (threadIdx.x >> 4);
    int ql = threadIdx.x & 15;
    if (node >= N) return;
    int beg = rowptr[node], end = rowptr[node + 1];
    float a[8];
    acc8(xb[(size_t)node * 16 + ql], a);   // uninitialized a? no: set below
    // (initialize properly)
    {
        uint4 u = xb[(size_t)node * 16 + ql];
        a[0] = __uint_as_float(u.x << 16);       a[1] = __uint_as_float(u.x & 0xffff0000u);
        a[2] = __uint_as_float(u.y << 16);       a[3] = __uint_as_float(u.y & 0xffff0000u);
        a[4] = __uint_as_float(u.z << 16);       a[5] = __uint_as_float(u.z & 0xffff0000u);
        a[6] = __uint_as_float(u.w << 16);       a[7] = __uint_as_float(u.w & 0xffff0000u);
    }
    int e = beg;
    while (e + 16 <= end) {                      // full chunks: 16 gathers fully unrolled
        int idx = csr[e + ql];
        #pragma unroll
        for (int d = 0; d < 16; ++d) {
            int s = __shfl(idx, d, 16);
            acc8(xb[(size_t)s * 16 + ql], a);
        }
        e += 16;
    }
    if (e < end) {                               // tail chunk
        int nb = end - e;
        int idx = (ql < nb) ? csr[e + ql] : 0;
        for (int d = 0; d < nb; ++d) {
            int s = __shfl(idx, d, 16);
            acc8(xb[(size_t)s * 16 + ql], a);
        }
    }
    float sc = 1.f / (float)(end - beg + 1);
    if (doscale) sc *= norm_s[node];
    uint4 o;
    o.x = pk2(a[0] * sc, a[1] * sc);
    o.y = pk2(a[2] * sc, a[3] * sc);
    o.z = pk2(a[4] * sc, a[5] * sc);
    o.w = pk2(a[6] * sc, a[7] * sc);
    outb[(size_t)node * 16 + ql] = o;
}

// ================= pull: sum of pre-scaled bf16 rows -> f32 Q, + ssum =================
__global__ __launch_bounds__(256) void k_pull3(
        const uint4* __restrict__ Pb, const int* __restrict__ rowptr,
        const int* __restrict__ csr, const float* __restrict__ norm_s,
        float* __restrict__ Q, float* __restrict__ ssum, int N) {
    int node = blockIdx.x * 16 + (threadIdx.x >> 4);
    int ql = threadIdx.x & 15;
    if (node >= N) return;
    int beg = rowptr[node], end = rowptr[node + 1];
    float a[8] = {0.f, 0.f, 0.f, 0.f, 0.f, 0.f, 0.f, 0.f};
    float ss = 0.f;
    int e = beg;
    while (e + 16 <= end) {
        int idx = csr[e + ql];
        #pragma unroll
        for (int d = 0; d < 16; ++d) {
            int s = __shfl(idx, d, 16);
            acc8(Pb[(size_t)s * 16 + ql], a);
            ss += norm_s[s];
        }
        e += 16;
    }
    if (e < end) {
        int nb = end - e;
        int idx = (ql < nb) ? csr[e + ql] : 0;
        for (int d = 0; d < nb; ++d) {
            int s = __shfl(idx, d, 16);
            acc8(Pb[(size_t)s * 16 + ql], a);
            ss += norm_s[s];
        }
    }
    float* qb = Q + (size_t)node * DD + ql * 8;
    *(float4*)qb       = make_float4(a[0], a[1], a[2], a[3]);
    *(float4*)(qb + 4) = make_float4(a[4], a[5], a[6], a[7]);
    if (ql == 0) ssum[node] = ss;
}

// ================= weight pre-combination =================
__global__ void k_wcomb(const float* __restrict__ A, const float* __restrict__ B,
                        float* __restrict__ C) {          // C[i] = A[i](128x128) @ B[i](128x16)
    int i = blockIdx.x;
    const float* Ai = A + (size_t)i * DD * DD;
    const float* Bi = B + (size_t)i * DD * DH;
    float* Ci = C + (size_t)i * DD * DH;
    for (int o = threadIdx.x; o < DD * DH; o += blockDim.x) {
        int r = o >> 4, c = o & 15;
        float acc = 0.f;
        #pragma unroll 8
        for (int k = 0; k < DD; ++k) acc += Ai[r * DD + k] * Bi[k * DH + c];
        Ci[o] = acc;
    }
}

// transposed variant: Mt[k][head*16+c] = (A[i] @ B[i])[k][c]
__global__ void k_wcombT(const float* __restrict__ A, const float* __restrict__ B,
                         float* __restrict__ Mt) {
    int i = blockIdx.x;
    const float* Ai = A + (size_t)i * DD * DD;
    const float* Bi = B + (size_t)i * DD * DH;
    for (int o = threadIdx.x; o < DD * DH; o += blockDim.x) {
        int r = o >> 4, c = o & 15;
        float acc = 0.f;
        #pragma unroll 8
        for (int k = 0; k < DD; ++k) acc += Ai[r * DD + k] * Bi[k * DH + c];
        Mt[r * DD + i * DH + c] = acc;
    }
}

__global__ void k_cvec(const float* __restrict__ b1, const float* __restrict__ b2,
                       const float* __restrict__ T, const float* __restrict__ W3,
                       float* __restrict__ cvec) {
    int idx = blockIdx.x * blockDim.x + threadIdx.x;
    if (idx >= NHEAD * DH) return;
    int i = idx >> 4, c = idx & 15;
    float acc = 0.f;
    for (int k = 0; k < DD; ++k)
        acc += b1[i * DD + k] * T[(size_t)i * DD * DH + k * DH + c]
             + b2[i * DD + k] * W3[(size_t)i * DD * DH + k * DH + c];
    cvec[idx] = acc;
}

// ================= fused tail: 4x4 register-tile GEMMs, transposed LDS operands ==========
__global__ __launch_bounds__(256) void k_tail(
        const float4* __restrict__ Qgt4, const float4* __restrict__ Qat4,
        const float* __restrict__ ssum, const float* __restrict__ indeg,
        const float* __restrict__ Mt, const float* __restrict__ cvec,
        const float* __restrict__ b3, const float* __restrict__ h,
        const float* __restrict__ ln_g, const float* __restrict__ ln_b,
        const float* __restrict__ fW1, const float* __restrict__ Fb1,
        const float* __restrict__ fW2, const float* __restrict__ Fb2,
        float* __restrict__ out, int N) {
    __shared__ float qT[2][DD][QPAD];     // [graph][k][row], 33792 B
    __shared__ float ws[32][DD];          // 16384 B
    int t = threadIdx.x;
    int tc = t & 31, tr = t >> 5;
    int C0 = 4 * tc, R0 = 4 * tr;
    int row0 = blockIdx.x * 32;

    // ---- stage Q transposed ----
    #pragma unroll
    for (int i = 0; i < 4; ++i) {
        int idx = t + 256 * i;
        int r = idx & 31, c = idx >> 5;
        int gr = row0 + r; if (gr >= N) gr = N - 1;
        float4 q0 = Qgt4[(size_t)gr * 32 + c];
        float4 q1 = Qat4[(size_t)gr * 32 + c];
        qT[0][4 * c + 0][r] = q0.x; qT[0][4 * c + 1][r] = q0.y;
        qT[0][4 * c + 2][r] = q0.z; qT[0][4 * c + 3][r] = q0.w;
        qT[1][4 * c + 0][r] = q1.x; qT[1][4 * c + 1][r] = q1.y;
        qT[1][4 * c + 2][r] = q1.z; qT[1][4 * c + 3][r] = q1.w;
    }
    int g = (C0 >> 5) & 1;      // graph of this thread's 4 columns

    // ---- GEMM1: xcat = Q_g @ M ----
    float acc[4][4] = {};
    for (int kt = 0; kt < 4; ++kt) {
        __syncthreads();
        const float4* wsrc = (const float4*)(Mt + kt * 32 * DD);
        float4* wdst = (float4*)&ws[0][0];
        #pragma unroll
        for (int i = 0; i < 4; ++i) wdst[t + 256 * i] = wsrc[t + 256 * i];
        __syncthreads();
        #pragma unroll 4
        for (int kk = 0; kk < 32; ++kk) {
            float4 av = *(const float4*)&qT[g][kt * 32 + kk][R0];
            float4 bv = *(const float4*)&ws[kk][C0];
            acc[0][0] += av.x * bv.x; acc[0][1] += av.x * bv.y;
            acc[0][2] += av.x * bv.z; acc[0][3] += av.x * bv.w;
            acc[1][0] += av.y * bv.x; acc[1][1] += av.y * bv.y;
            acc[1][2] += av.y * bv.z; acc[1][3] += av.y * bv.w;
            acc[2][0] += av.z * bv.x; acc[2][1] += av.z * bv.y;
            acc[2][2] += av.z * bv.z; acc[2][3] += av.z * bv.w;
            acc[3][0] += av.w * bv.x; acc[3][1] += av.w * bv.y;
            acc[3][2] += av.w * bv.z; acc[3][3] += av.w * bv.w;
        }
    }
    // ---- epilogue1: (acc + ss*c)*nd + b3, LN over row, + residual ----
    float4 cv  = *(const float4*)&cvec[C0];
    float4 b3v = *(const float4*)&b3[C0];
    float4 glv = *(const float4*)&ln_g[C0];
    float4 blv = *(const float4*)&ln_b[C0];
    float xr[4][4];
    #pragma unroll
    for (int i = 0; i < 4; ++i) {
        int row = row0 + R0 + i;
        int rc = row < N ? row : N - 1;
        float ss = ssum[g * N + rc];
        float id = indeg[g * N + rc];
        float nd = id > 0.f ? rsqrtf(id) : 0.f;
        float v0 = (acc[i][0] + ss * cv.x) * nd + b3v.x;
        float v1 = (acc[i][1] + ss * cv.y) * nd + b3v.y;
        float v2 = (acc[i][2] + ss * cv.z) * nd + b3v.z;
        float v3 = (acc[i][3] + ss * cv.w) * nd + b3v.w;
        float s = v0 + v1 + v2 + v3;
        float s2 = v0 * v0 + v1 * v1 + v2 * v2 + v3 * v3;
        for (int o = 16; o > 0; o >>= 1) { s += __shfl_xor(s, o); s2 += __shfl_xor(s2, o); }
        float mu = s * (1.f / DD);
        float var = s2 * (1.f / DD) - mu * mu;
        float rs = rsqrtf(var + EPS);
        float4 hv = *(const float4*)&h[(size_t)rc * DD + C0];
        xr[i][0] = hv.x + (v0 - mu) * rs * glv.x + blv.x;
        xr[i][1] = hv.y + (v1 - mu) * rs * glv.y + blv.y;
        xr[i][2] = hv.z + (v2 - mu) * rs * glv.z + blv.z;
        xr[i][3] = hv.w + (v3 - mu) * rs * glv.w + blv.w;
    }
    __syncthreads();                       // all qT reads done before overwrite
    #pragma unroll
    for (int j = 0; j < 4; ++j)            // xT = qT[0]
        *(float4*)&qT[0][C0 + j][R0] =
            make_float4(xr[0][j], xr[1][j], xr[2][j], xr[3][j]);

    // ---- GEMM2: f1 = relu(x @ fW1 + Fb1) ----
    float ac2[4][4] = {};
    for (int kt = 0; kt < 4; ++kt) {
        __syncthreads();
        const float4* wsrc = (const float4*)(fW1 + kt * 32 * DD);
        float4* wdst = (float4*)&ws[0][0];
        #pragma unroll
        for (int i = 0; i < 4; ++i) wdst[t + 256 * i] = wsrc[t + 256 * i];
        __syncthreads();
        #pragma unroll 4
        for (int kk = 0; kk < 32; ++kk) {
            float4 av = *(const float4*)&qT[0][kt * 32 + kk][R0];
            float4 bv = *(const float4*)&ws[kk][C0];
            ac2[0][0] += av.x * bv.x; ac2[0][1] += av.x * bv.y;
            ac2[0][2] += av.x * bv.z; ac2[0][3] += av.x * bv.w;
            ac2[1][0] += av.y * bv.x; ac2[1][1] += av.y * bv.y;
            ac2[1][2] += av.y * bv.z; ac2[1][3] += av.y * bv.w;
            ac2[2][0] += av.z * bv.x; ac2[2][1] += av.z * bv.y;
            ac2[2][2] += av.z * bv.z; ac2[2][3] += av.z * bv.w;
            ac2[3][0] += av.w * bv.x; ac2[3][1] += av.w * bv.y;
            ac2[3][2] += av.w * bv.z; ac2[3][3] += av.w * bv.w;
        }
    }
    float4 fbv = *(const float4*)&Fb1[C0];
    #pragma unroll
    for (int j = 0; j < 4; ++j) {          // f1T = qT[1]
        float bj = j == 0 ? fbv.x : j == 1 ? fbv.y : j == 2 ? fbv.z : fbv.w;
        float w0 = ac2[0][j] + bj, w1 = ac2[1][j] + bj;
        float w2 = ac2[2][j] + bj, w3 = ac2[3][j] + bj;
        *(float4*)&qT[1][C0 + j][R0] =
            make_float4(w0 > 0.f ? w0 : 0.f, w1 > 0.f ? w1 : 0.f,
                        w2 > 0.f ? w2 : 0.f, w3 > 0.f ? w3 : 0.f);
    }

    // ---- GEMM3: out = x + LN(f1 @ fW2 + Fb2) ----
    float ac3[4][4] = {};
    for (int kt = 0; kt < 4; ++kt) {
        __syncthreads();                   // orders f1T writes before reads (kt=0)
        const float4* wsrc = (const float4*)(fW2 + kt * 32 * DD);
        float4* wdst = (float4*)&ws[0][0];
        #pragma unroll
        for (int i = 0; i < 4; ++i) wdst[t + 256 * i] = wsrc[t + 256 * i];
        __syncthreads();
        #pragma unroll 4
        for (int kk = 0; kk < 32; ++kk) {
            float4 av = *(const float4*)&qT[1][kt * 32 + kk][R0];
            float4 bv = *(const float4*)&ws[kk][C0];
            ac3[0][0] += av.x * bv.x; ac3[0][1] += av.x * bv.y;
            ac3[0][2] += av.x * bv.z; ac3[0][3] += av.x * bv.w;
            ac3[1][0] += av.y * bv.x; ac3[1][1] += av.y * bv.y;
            ac3[1][2] += av.y * bv.z; ac3[1][3] += av.y * bv.w;
            ac3[2][0] += av.z * bv.x; ac3[2][1] += av.z * bv.y;
            ac3[2][2] += av.z * bv.z; ac3[2][3] += av.z * bv.w;
            ac3[3][0] += av.w * bv.x; ac3[3][1] += av.w * bv.y;
            ac3[3][2] += av.w * bv.z; ac3[3][3] += av.w * bv.w;
        }
    }
    float4 gbv = *(const float4*)&Fb2[C0];
    #pragma unroll
    for (int i = 0; i < 4; ++i) {
        int row = row0 + R0 + i;
        float v0 = ac3[i][0] + gbv.x;
        float v1 = ac3[i][1] + gbv.y;
        float v2 = ac3[i][2] + gbv.z;
        float v3 = ac3[i][3] + gbv.w;
        float s = v0 + v1 + v2 + v3;
        float s2 = v0 * v0 + v1 * v1 + v2 * v2 + v3 * v3;
        for (int o = 16; o > 0; o >>= 1) { s += __shfl_xor(s, o); s2 += __shfl_xor(s2, o); }
        float mu = s * (1.f / DD);
        float var = s2 * (1.f / DD) - mu * mu;
        float rs = rsqrtf(var + EPS);
        if (row < N) {
            *(float4*)&out[(size_t)row * DD + C0] =
                make_float4(xr[i][0] + (v0 - mu) * rs * glv.x + blv.x,
                            xr[i][1] + (v1 - mu) * rs * glv.y + blv.y,
                            xr[i][2] + (v2 - mu) * rs * glv.z + blv.z,
                            xr[i][3] + (v3 - mu) * rs * glv.w + blv.w);
        }
    }
}

extern "C" void kernel_launch(void* const* d_in, const int* in_sizes, int n_in,
                              void* d_out, int out_size, void* d_ws, size_t ws_size,
                              hipStream_t stream) {
    const float* h      = (const float*)d_in[0];
    const int*   gt_src = (const int*)d_in[1];
    const int*   gt_dst = (const int*)d_in[2];
    const int*   at_src = (const int*)d_in[3];
    const int*   at_dst = (const int*)d_in[4];
    const float* W1     = (const float*)d_in[5];
    const float* b1     = (const float*)d_in[6];
    const float* W2     = (const float*)d_in[7];
    const float* b2     = (const float*)d_in[8];
    const float* W3     = (const float*)d_in[9];
    const float* b3     = (const float*)d_in[10];
    const float* fW1    = (const float*)d_in[11];
    const float* fb1    = (const float*)d_in[12];
    const float* fW2    = (const float*)d_in[13];
    const float* fb2    = (const float*)d_in[14];
    const float* ln_g   = (const float*)d_in[15];
    const float* ln_b   = (const float*)d_in[16];

    const int E = in_sizes[1];
    const int N = in_sizes[0] / DD;
    const size_t NB = (size_t)N * DD;
    const int N2 = 2 * N;
    const int Btot = (N2 + BWIDTH - 1) >> BSH;
    const int n1 = 2 * Btot * NBLK1;

    // ---- workspace layout ----
    float* w = (float*)d_ws;
    float* Qgt = w;                              // NB f32 (25.6 MB)
    unsigned short* hb    = (unsigned short*)(Qgt + NB);   // NB bf16
    unsigned short* bufAb = hb + NB;                       // NB bf16
    unsigned short* bufBb = bufAb + NB;                    // NB bf16
    float* sm = (float*)(bufBb + NB);
    float* norms = sm;  sm += N2;
    float* indeg = sm;  sm += N2;
    float* ssum  = sm;  sm += N2;
    float* Tm    = sm;  sm += (size_t)NHEAD * DD * DH;
    float* Mt    = sm;  sm += DD * DD;
    float* cvec  = sm;  sm += NHEAD * DH + 32;
    int* ip = (int*)sm;
    int* rowptr = ip;  ip += ((N2 + 1 + 3) & ~3);
    int* csr    = ip;  ip += 2 * E;
    int* blkcnt = ip;  ip += ((n1 + 1 + 3) & ~3);
    int* scn    = ip;  ip += ((n1 + 1 + 3) & ~3);
    int* part   = ip;  ip += 256;
    // CSR-build scratch aliased over Qgt (written only later, in pass 3)
    int2* pairs = (int2*)Qgt;                    // 2E int2 = 9.6 MB
    int*  svals = (int*)(pairs + 2 * E);         // 2E int  = 4.8 MB
    float* Qat  = (float*)d_out;                 // reuse d_out; overwritten by k_tail

    // weight pre-combination
    k_wcomb <<<NHEAD, 256, 0, stream>>>(W2, W3, Tm);
    k_wcombT<<<NHEAD, 256, 0, stream>>>(W1, Tm, Mt);
    k_cvec  <<<1, 128, 0, stream>>>(b1, b2, Tm, W3, cvec);

    const int TB = 256;
    // h -> bf16
    k_h2b<<<(int)(NB / 4 + TB - 1) / TB, TB, 0, stream>>>((const float4*)h, (ushort4*)hb,
                                                          (int)(NB / 4));
    // CSR build (no global atomics)
    k_p1count<<<NBLK1, 256, 0, stream>>>(gt_src, gt_dst, at_src, at_dst, blkcnt, E, N, Btot);
    int nsb = (n1 + 1023) / 1024;
    k_scan1<<<nsb, 256, 0, stream>>>(blkcnt, scn, part, n1);
    k_scan2<<<1, 256, 0, stream>>>(part, nsb);
    k_scan3<<<(n1 + TB - 1) / TB, TB, 0, stream>>>(scn, part, n1, 4 * E);
    k_p1scatter<<<NBLK1, 256, 0, stream>>>(gt_src, gt_dst, at_src, at_dst, scn,
                                           pairs, svals, E, N, Btot);
    k_p2<<<Btot, 256, 0, stream>>>(pairs, svals, scn, rowptr, csr, indeg, norms,
                                   E, N2, Btot);

    // pull passes (bf16 uint4 gathers): 16 nodes/block, 16 lanes/node
    const int pgrid = (N + 15) / 16;
    for (int g = 0; g < 2; ++g) {
        const int* rp = rowptr + g * N;
        const float* ns = norms + g * N;
        float* Q = g ? Qat : Qgt;
        k_pull_avg<<<pgrid, 256, 0, stream>>>((const uint4*)hb, rp, csr, ns,
                                              (uint4*)bufAb, N, 0);
        k_pull_avg<<<pgrid, 256, 0, stream>>>((const uint4*)bufAb, rp, csr, ns,
                                              (uint4*)bufBb, N, 1);
        k_pull3<<<pgrid, 256, 0, stream>>>((const uint4*)bufBb, rp, csr, ns,
                                           Q, ssum + g * N, N);
    }

    // fused dense tail (32 rows/block, 4x4 register tiles)
    k_tail<<<(N + 31) / 32, 256, 0, stream>>>((const float4*)Qgt, (const float4*)Qat,
                                              ssum, indeg, Mt, cvec, b3, h, ln_g, ln_b,
                                              fW1, fb1, fW2, fb2, (float*)d_out, N);
}

// Round 9
// 394.494 us; speedup vs baseline: 1.1810x; 1.1810x over previous
//
#include <hip/hip_runtime.h>

#define DD 128
#define NHEAD 8
#define DH 16
#define EPS 1e-5f
#define BSH 9                 // bucket width 512 nodes
#define BWIDTH 512
#define NBLK1 256             // pass-1 blocks

// ---------- bf16 helpers (OCP bf16 = f32 upper half, RNE) ----------
__device__ inline float4 up4(ushort4 u) {
    return make_float4(__uint_as_float((unsigned)u.x << 16),
                       __uint_as_float((unsigned)u.y << 16),
                       __uint_as_float((unsigned)u.z << 16),
                       __uint_as_float((unsigned)u.w << 16));
}
__device__ inline unsigned short f2b(float f) {
    unsigned u = __float_as_uint(f);
    u += 0x7fffu + ((u >> 16) & 1);
    return (unsigned short)(u >> 16);
}

// LDS swizzle for transposed tiles: word(k,r) = k*32 + (r ^ (((k>>2)&7)<<2)).
// Keeps 16B alignment (XOR operand multiple of 4); A-reads stay wave-broadcast;
// column-writes (k = C0+j, (k>>2) = tc) spread over 8 start banks -> 4-way max.
__device__ inline int qw(int k, int r) { return (k << 5) + (r ^ (((k >> 2) & 7) << 2)); }

// ================= h -> bf16 copy =================
__global__ void k_h2b(const float4* __restrict__ h4, ushort4* __restrict__ hb, int n4) {
    int i = blockIdx.x * 256 + threadIdx.x;
    if (i < n4) {
        float4 v = h4[i];
        hb[i] = make_ushort4(f2b(v.x), f2b(v.y), f2b(v.z), f2b(v.w));
    }
}

// ================= pass 1a: per-block bucket histograms =================
__global__ __launch_bounds__(256) void k_p1count(
        const int* __restrict__ gs, const int* __restrict__ gd,
        const int* __restrict__ as_, const int* __restrict__ ad,
        int* __restrict__ blkcnt, int E, int N, int Btot) {
    __shared__ int cnts[512];
    for (int j = threadIdx.x; j < 2 * Btot; j += 256) cnts[j] = 0;
    __syncthreads();
    int E2 = 2 * E;
    for (int i = blockIdx.x * 256 + threadIdx.x; i < E2; i += NBLK1 * 256) {
        int g = (i >= E);
        int e = g ? i - E : i;
        int s = g ? as_[e] : gs[e];
        int d = g ? ad[e] : gd[e];
        int cd = d + g * N, cs = s + g * N;
        atomicAdd(&cnts[cd >> BSH], 1);
        atomicAdd(&cnts[Btot + (cs >> BSH)], 1);
    }
    __syncthreads();
    for (int j = threadIdx.x; j < 2 * Btot; j += 256)
        blkcnt[j * NBLK1 + blockIdx.x] = cnts[j];
}

// ================= 3-stage scan =================
__global__ void k_scan1(const int* __restrict__ cnt, int* __restrict__ outv,
                        int* __restrict__ part, int n) {
    __shared__ int wsums[4];
    int t = threadIdx.x;
    int base = blockIdx.x * 1024 + t * 4;
    int v0 = 0, v1 = 0, v2 = 0, v3 = 0;
    if (base + 3 < n) {
        int4 q = *(const int4*)(cnt + base);
        v0 = q.x; v1 = q.y; v2 = q.z; v3 = q.w;
    } else {
        if (base < n)     v0 = cnt[base];
        if (base + 1 < n) v1 = cnt[base + 1];
        if (base + 2 < n) v2 = cnt[base + 2];
        if (base + 3 < n) v3 = cnt[base + 3];
    }
    int s0 = v0, s1 = s0 + v1, s2 = s1 + v2, s3 = s2 + v3;
    int x = s3;
    int lane = t & 63, w = t >> 6;
    for (int o = 1; o < 64; o <<= 1) { int u = __shfl_up(x, o); if (lane >= o) x += u; }
    if (lane == 63) wsums[w] = x;
    __syncthreads();
    int wo = 0;
    for (int i = 0; i < w; ++i) wo += wsums[i];
    int excl = wo + x - s3;
    if (base < n)     outv[base]     = excl;
    if (base + 1 < n) outv[base + 1] = excl + s0;
    if (base + 2 < n) outv[base + 2] = excl + s1;
    if (base + 3 < n) outv[base + 3] = excl + s2;
    if (t == 255) part[blockIdx.x] = wo + x;
}

__global__ void k_scan2(int* __restrict__ part, int nb) {
    __shared__ int ws[4];
    int t = threadIdx.x;
    int v = (t < nb) ? part[t] : 0;
    int x = v;
    int lane = t & 63, w = t >> 6;
    for (int o = 1; o < 64; o <<= 1) { int u = __shfl_up(x, o); if (lane >= o) x += u; }
    if (lane == 63) ws[w] = x;
    __syncthreads();
    int wo = 0;
    for (int i = 0; i < w; ++i) wo += ws[i];
    if (t < nb) part[t] = wo + x - v;
}

__global__ void k_scan3(int* __restrict__ outv, const int* __restrict__ part, int n, int total) {
    int i = blockIdx.x * blockDim.x + threadIdx.x;
    if (i < n) outv[i] += part[i >> 10];
    if (i == 0) outv[n] = total;
}

// ================= pass 1b: scatter edges into bucket regions =================
__global__ __launch_bounds__(256) void k_p1scatter(
        const int* __restrict__ gs, const int* __restrict__ gd,
        const int* __restrict__ as_, const int* __restrict__ ad,
        const int* __restrict__ scn, int2* __restrict__ pairs, int* __restrict__ svals,
        int E, int N, int Btot) {
    __shared__ int cur[512];
    for (int j = threadIdx.x; j < 2 * Btot; j += 256)
        cur[j] = scn[j * NBLK1 + blockIdx.x];
    __syncthreads();
    int E2 = 2 * E;
    for (int i = blockIdx.x * 256 + threadIdx.x; i < E2; i += NBLK1 * 256) {
        int g = (i >= E);
        int e = g ? i - E : i;
        int s = g ? as_[e] : gs[e];
        int d = g ? ad[e] : gd[e];
        int cd = d + g * N, cs = s + g * N;
        int pd = atomicAdd(&cur[cd >> BSH], 1);
        pairs[pd] = make_int2(cd, s);
        int ps = atomicAdd(&cur[Btot + (cs >> BSH)], 1);
        svals[ps - E2] = cs;
    }
}

// ================= pass 2: per-bucket CSR + indeg + norms =================
__global__ __launch_bounds__(256) void k_p2(
        const int2* __restrict__ pairs, const int* __restrict__ svals,
        const int* __restrict__ scn, int* __restrict__ rowptr, int* __restrict__ csr,
        float* __restrict__ indeg, float* __restrict__ norms,
        int E, int N2, int Btot) {
    __shared__ int hist[BWIDTH];
    __shared__ int offs[BWIDTH];
    __shared__ int cur[BWIDTH];
    __shared__ int ws4[4];
    int b = blockIdx.x, t = threadIdx.x;
    int node0 = b << BSH;
    int W = N2 - node0; if (W > BWIDTH) W = BWIDTH;
    int Sd = scn[b * NBLK1], Ed = scn[(b + 1) * NBLK1];
    hist[t] = 0; hist[t + 256] = 0;
    __syncthreads();
    for (int i = Sd + t; i < Ed; i += 256) {
        int2 p = pairs[i];
        atomicAdd(&hist[p.x - node0], 1);
    }
    __syncthreads();
    int a0 = hist[2 * t], a1 = hist[2 * t + 1];
    int sum2 = a0 + a1;
    int lane = t & 63, w = t >> 6;
    int x = sum2;
    for (int o = 1; o < 64; o <<= 1) { int u = __shfl_up(x, o); if (lane >= o) x += u; }
    if (lane == 63) ws4[w] = x;
    __syncthreads();
    int wo = 0;
    for (int i = 0; i < w; ++i) wo += ws4[i];
    int excl2 = wo + x - sum2;
    offs[2 * t] = excl2; offs[2 * t + 1] = excl2 + a0;
    cur[t] = 0; cur[t + 256] = 0;
    __syncthreads();
    for (int j = t; j < W; j += 256) {
        rowptr[node0 + j] = Sd + offs[j];
        indeg[node0 + j] = (float)hist[j];
    }
    if (b == 0 && t == 0) rowptr[N2] = 2 * E;
    for (int i = Sd + t; i < Ed; i += 256) {
        int2 p = pairs[i];
        int l = p.x - node0;
        int pos = atomicAdd(&cur[l], 1);
        csr[Sd + offs[l] + pos] = p.y;
    }
    __syncthreads();
    hist[t] = 0; hist[t + 256] = 0;
    __syncthreads();
    int Ss = scn[(Btot + b) * NBLK1] - 2 * E;
    int Es = scn[(Btot + b + 1) * NBLK1] - 2 * E;
    for (int i = Ss + t; i < Es; i += 256)
        atomicAdd(&hist[svals[i] - node0], 1);
    __syncthreads();
    for (int j = t; j < W; j += 256) {
        int od = hist[j];
        norms[node0 + j] = od > 0 ? rsqrtf((float)od) : 0.f;
    }
}

// ================= pull: avg (SAGE) over bf16 rows, optional norm-scale (R6 form) ========
__global__ __launch_bounds__(256) void k_pull_avg(
        const ushort4* __restrict__ xb, const int* __restrict__ rowptr,
        const int* __restrict__ csr, const float* __restrict__ norm_s,
        ushort4* __restrict__ outb, int N, int doscale) {
    int node = blockIdx.x * 8 + (threadIdx.x >> 5);
    int lane = threadIdx.x & 31;
    if (node >= N) return;
    int beg = rowptr[node], end = rowptr[node + 1];
    float4 a = up4(xb[(size_t)node * 32 + lane]);          // self term
    int e = beg;
    while (e < end) {
        int nb = end - e; if (nb > 32) nb = 32;
        int idx = (lane < nb) ? csr[e + lane] : 0;
        #pragma unroll 4
        for (int d = 0; d < nb; ++d) {
            int s = __shfl(idx, d, 32);
            float4 v = up4(xb[(size_t)s * 32 + lane]);
            a.x += v.x; a.y += v.y; a.z += v.z; a.w += v.w;
        }
        e += nb;
    }
    float sc = 1.f / (float)(end - beg + 1);
    if (doscale) sc *= norm_s[node];
    outb[(size_t)node * 32 + lane] =
        make_ushort4(f2b(a.x * sc), f2b(a.y * sc), f2b(a.z * sc), f2b(a.w * sc));
}

// ================= pull: plain sum of pre-scaled bf16 rows -> f32 Q, + ssum (R6 form) =====
__global__ __launch_bounds__(256) void k_pull3(
        const ushort4* __restrict__ Pb, const int* __restrict__ rowptr,
        const int* __restrict__ csr, const float* __restrict__ norm_s,
        float4* __restrict__ Q, float* __restrict__ ssum, int N) {
    int node = blockIdx.x * 8 + (threadIdx.x >> 5);
    int lane = threadIdx.x & 31;
    if (node >= N) return;
    int beg = rowptr[node], end = rowptr[node + 1];
    float4 a = make_float4(0.f, 0.f, 0.f, 0.f);
    float ss = 0.f;
    int e = beg;
    while (e < end) {
        int nb = end - e; if (nb > 32) nb = 32;
        int idx = (lane < nb) ? csr[e + lane] : 0;
        #pragma unroll 4
        for (int d = 0; d < nb; ++d) {
            int s = __shfl(idx, d, 32);
            float4 v = up4(Pb[(size_t)s * 32 + lane]);
            a.x += v.x; a.y += v.y; a.z += v.z; a.w += v.w;
            ss += norm_s[s];
        }
        e += nb;
    }
    Q[(size_t)node * 32 + lane] = a;
    if (lane == 0) ssum[node] = ss;
}

// ================= weight pre-combination =================
__global__ void k_wcomb(const float* __restrict__ A, const float* __restrict__ B,
                        float* __restrict__ C) {          // C[i] = A[i](128x128) @ B[i](128x16)
    int i = blockIdx.x;
    const float* Ai = A + (size_t)i * DD * DD;
    const float* Bi = B + (size_t)i * DD * DH;
    float* Ci = C + (size_t)i * DD * DH;
    for (int o = threadIdx.x; o < DD * DH; o += blockDim.x) {
        int r = o >> 4, c = o & 15;
        float acc = 0.f;
        #pragma unroll 8
        for (int k = 0; k < DD; ++k) acc += Ai[r * DD + k] * Bi[k * DH + c];
        Ci[o] = acc;
    }
}

// transposed variant: Mt[k][head*16+c] = (A[i] @ B[i])[k][c]
__global__ void k_wcombT(const float* __restrict__ A, const float* __restrict__ B,
                         float* __restrict__ Mt) {
    int i = blockIdx.x;
    const float* Ai = A + (size_t)i * DD * DD;
    const float* Bi = B + (size_t)i * DD * DH;
    for (int o = threadIdx.x; o < DD * DH; o += blockDim.x) {
        int r = o >> 4, c = o & 15;
        float acc = 0.f;
        #pragma unroll 8
        for (int k = 0; k < DD; ++k) acc += Ai[r * DD + k] * Bi[k * DH + c];
        Mt[r * DD + i * DH + c] = acc;
    }
}

__global__ void k_cvec(const float* __restrict__ b1, const float* __restrict__ b2,
                       const float* __restrict__ T, const float* __restrict__ W3,
                       float* __restrict__ cvec) {
    int idx = blockIdx.x * blockDim.x + threadIdx.x;
    if (idx >= NHEAD * DH) return;
    int i = idx >> 4, c = idx & 15;
    float acc = 0.f;
    for (int k = 0; k < DD; ++k)
        acc += b1[i * DD + k] * T[(size_t)i * DD * DH + k * DH + c]
             + b2[i * DD + k] * W3[(size_t)i * DD * DH + k * DH + c];
    cvec[idx] = acc;
}

// ================= fused tail: 4x4 register-tile GEMMs, XOR-swizzled transposed tiles =====
__global__ __launch_bounds__(256) void k_tail(
        const float4* __restrict__ Qgt4, const float4* __restrict__ Qat4,
        const float* __restrict__ ssum, const float* __restrict__ indeg,
        const float* __restrict__ Mt, const float* __restrict__ cvec,
        const float* __restrict__ b3, const float* __restrict__ h,
        const float* __restrict__ ln_g, const float* __restrict__ ln_b,
        const float* __restrict__ fW1, const float* __restrict__ Fb1,
        const float* __restrict__ fW2, const float* __restrict__ Fb2,
        float* __restrict__ out, int N) {
    __shared__ float qT[2][DD * 32];      // [graph][swizzled k*32+r], 32768 B
    __shared__ float ws[32][DD];          // 16384 B
    int t = threadIdx.x;
    int tc = t & 31, tr = t >> 5;
    int C0 = 4 * tc, R0 = 4 * tr;
    int row0 = blockIdx.x * 32;

    // ---- stage Q transposed (swizzled scalar writes: conflict-free) ----
    #pragma unroll
    for (int i = 0; i < 4; ++i) {
        int idx = t + 256 * i;
        int r = idx & 31, c = idx >> 5;
        int gr = row0 + r; if (gr >= N) gr = N - 1;
        float4 q0 = Qgt4[(size_t)gr * 32 + c];
        float4 q1 = Qat4[(size_t)gr * 32 + c];
        int rx = r ^ ((c & 7) << 2);               // xs(k)=4*((k>>2)&7), k=4c+j -> 4*(c&7)
        qT[0][(4 * c + 0) * 32 + rx] = q0.x; qT[0][(4 * c + 1) * 32 + rx] = q0.y;
        qT[0][(4 * c + 2) * 32 + rx] = q0.z; qT[0][(4 * c + 3) * 32 + rx] = q0.w;
        qT[1][(4 * c + 0) * 32 + rx] = q1.x; qT[1][(4 * c + 1) * 32 + rx] = q1.y;
        qT[1][(4 * c + 2) * 32 + rx] = q1.z; qT[1][(4 * c + 3) * 32 + rx] = q1.w;
    }
    int g = (C0 >> 5) & 1;      // graph of this thread's 4 columns

    // ---- GEMM1: xcat = Q_g @ M ----
    float acc[4][4] = {};
    for (int kt = 0; kt < 4; ++kt) {
        __syncthreads();
        const float4* wsrc = (const float4*)(Mt + kt * 32 * DD);
        float4* wdst = (float4*)&ws[0][0];
        #pragma unroll
        for (int i = 0; i < 4; ++i) wdst[t + 256 * i] = wsrc[t + 256 * i];
        __syncthreads();
        #pragma unroll 4
        for (int kk = 0; kk < 32; ++kk) {
            float4 av = *(const float4*)&qT[g][qw(kt * 32 + kk, R0)];
            float4 bv = *(const float4*)&ws[kk][C0];
            acc[0][0] += av.x * bv.x; acc[0][1] += av.x * bv.y;
            acc[0][2] += av.x * bv.z; acc[0][3] += av.x * bv.w;
            acc[1][0] += av.y * bv.x; acc[1][1] += av.y * bv.y;
            acc[1][2] += av.y * bv.z; acc[1][3] += av.y * bv.w;
            acc[2][0] += av.z * bv.x; acc[2][1] += av.z * bv.y;
            acc[2][2] += av.z * bv.z; acc[2][3] += av.z * bv.w;
            acc[3][0] += av.w * bv.x; acc[3][1] += av.w * bv.y;
            acc[3][2] += av.w * bv.z; acc[3][3] += av.w * bv.w;
        }
    }
    // ---- epilogue1: (acc + ss*c)*nd + b3, LN over row, + residual ----
    float4 cv  = *(const float4*)&cvec[C0];
    float4 b3v = *(const float4*)&b3[C0];
    float4 glv = *(const float4*)&ln_g[C0];
    float4 blv = *(const float4*)&ln_b[C0];
    float xr[4][4];
    #pragma unroll
    for (int i = 0; i < 4; ++i) {
        int row = row0 + R0 + i;
        int rc = row < N ? row : N - 1;
        float ss = ssum[g * N + rc];
        float id = indeg[g * N + rc];
        float nd = id > 0.f ? rsqrtf(id) : 0.f;
        float v0 = (acc[i][0] + ss * cv.x) * nd + b3v.x;
        float v1 = (acc[i][1] + ss * cv.y) * nd + b3v.y;
        float v2 = (acc[i][2] + ss * cv.z) * nd + b3v.z;
        float v3 = (acc[i][3] + ss * cv.w) * nd + b3v.w;
        float s = v0 + v1 + v2 + v3;
        float s2 = v0 * v0 + v1 * v1 + v2 * v2 + v3 * v3;
        for (int o = 16; o > 0; o >>= 1) { s += __shfl_xor(s, o); s2 += __shfl_xor(s2, o); }
        float mu = s * (1.f / DD);
        float var = s2 * (1.f / DD) - mu * mu;
        float rs = rsqrtf(var + EPS);
        float4 hv = *(const float4*)&h[(size_t)rc * DD + C0];
        xr[i][0] = hv.x + (v0 - mu) * rs * glv.x + blv.x;
        xr[i][1] = hv.y + (v1 - mu) * rs * glv.y + blv.y;
        xr[i][2] = hv.z + (v2 - mu) * rs * glv.z + blv.z;
        xr[i][3] = hv.w + (v3 - mu) * rs * glv.w + blv.w;
    }
    __syncthreads();                       // all qT reads done before overwrite
    {
        int rx = R0 ^ ((tc & 7) << 2);     // (k>>2)&7 = tc&7 for k = C0+j
        #pragma unroll
        for (int j = 0; j < 4; ++j)        // xT -> qT[0] (b128, 4-way max)
            *(float4*)&qT[0][(C0 + j) * 32 + rx] =
                make_float4(xr[0][j], xr[1][j], xr[2][j], xr[3][j]);
    }

    // ---- GEMM2: f1 = relu(x @ fW1 + Fb1) ----
    float ac2[4][4] = {};
    for (int kt = 0; kt < 4; ++kt) {
        __syncthreads();
        const float4* wsrc = (const float4*)(fW1 + kt * 32 * DD);
        float4* wdst = (float4*)&ws[0][0];
        #pragma unroll
        for (int i = 0; i < 4; ++i) wdst[t + 256 * i] = wsrc[t + 256 * i];
        __syncthreads();
        #pragma unroll 4
        for (int kk = 0; kk < 32; ++kk) {
            float4 av = *(const float4*)&qT[0][qw(kt * 32 + kk, R0)];
            float4 bv = *(const float4*)&ws[kk][C0];
            ac2[0][0] += av.x * bv.x; ac2[0][1] += av.x * bv.y;
            ac2[0][2] += av.x * bv.z; ac2[0][3] += av.x * bv.w;
            ac2[1][0] += av.y * bv.x; ac2[1][1] += av.y * bv.y;
            ac2[1][2] += av.y * bv.z; ac2[1][3] += av.y * bv.w;
            ac2[2][0] += av.z * bv.x; ac2[2][1] += av.z * bv.y;
            ac2[2][2] += av.z * bv.z; ac2[2][3] += av.z * bv.w;
            ac2[3][0] += av.w * bv.x; ac2[3][1] += av.w * bv.y;
            ac2[3][2] += av.w * bv.z; ac2[3][3] += av.w * bv.w;
        }
    }
    float4 fbv = *(const float4*)&Fb1[C0];
    __syncthreads();                       // qT[1] reads (GEMM1 staging) long done; order f1T write
    {
        int rx = R0 ^ ((tc & 7) << 2);
        #pragma unroll
        for (int j = 0; j < 4; ++j) {      // f1T -> qT[1]
            float bj = j == 0 ? fbv.x : j == 1 ? fbv.y : j == 2 ? fbv.z : fbv.w;
            float w0 = ac2[0][j] + bj, w1 = ac2[1][j] + bj;
            float w2 = ac2[2][j] + bj, w3 = ac2[3][j] + bj;
            *(float4*)&qT[1][(C0 + j) * 32 + rx] =
                make_float4(w0 > 0.f ? w0 : 0.f, w1 > 0.f ? w1 : 0.f,
                            w2 > 0.f ? w2 : 0.f, w3 > 0.f ? w3 : 0.f);
        }
    }

    // ---- GEMM3: out = x + LN(f1 @ fW2 + Fb2) ----
    float ac3[4][4] = {};
    for (int kt = 0; kt < 4; ++kt) {
        __syncthreads();                   // orders f1T writes before reads (kt=0)
        const float4* wsrc = (const float4*)(fW2 + kt * 32 * DD);
        float4* wdst = (float4*)&ws[0][0];
        #pragma unroll
        for (int i = 0; i < 4; ++i) wdst[t + 256 * i] = wsrc[t + 256 * i];
        __syncthreads();
        #pragma unroll 4
        for (int kk = 0; kk < 32; ++kk) {
            float4 av = *(const float4*)&qT[1][qw(kt * 32 + kk, R0)];
            float4 bv = *(const float4*)&ws[kk][C0];
            ac3[0][0] += av.x * bv.x; ac3[0][1] += av.x * bv.y;
            ac3[0][2] += av.x * bv.z; ac3[0][3] += av.x * bv.w;
            ac3[1][0] += av.y * bv.x; ac3[1][1] += av.y * bv.y;
            ac3[1][2] += av.y * bv.z; ac3[1][3] += av.y * bv.w;
            ac3[2][0] += av.z * bv.x; ac3[2][1] += av.z * bv.y;
            ac3[2][2] += av.z * bv.z; ac3[2][3] += av.z * bv.w;
            ac3[3][0] += av.w * bv.x; ac3[3][1] += av.w * bv.y;
            ac3[3][2] += av.w * bv.z; ac3[3][3] += av.w * bv.w;
        }
    }
    float4 gbv = *(const float4*)&Fb2[C0];
    #pragma unroll
    for (int i = 0; i < 4; ++i) {
        int row = row0 + R0 + i;
        float v0 = ac3[i][0] + gbv.x;
        float v1 = ac3[i][1] + gbv.y;
        float v2 = ac3[i][2] + gbv.z;
        float v3 = ac3[i][3] + gbv.w;
        float s = v0 + v1 + v2 + v3;
        float s2 = v0 * v0 + v1 * v1 + v2 * v2 + v3 * v3;
        for (int o = 16; o > 0; o >>= 1) { s += __shfl_xor(s, o); s2 += __shfl_xor(s2, o); }
        float mu = s * (1.f / DD);
        float var = s2 * (1.f / DD) - mu * mu;
        float rs = rsqrtf(var + EPS);
        if (row < N) {
            *(float4*)&out[(size_t)row * DD + C0] =
                make_float4(xr[i][0] + (v0 - mu) * rs * glv.x + blv.x,
                            xr[i][1] + (v1 - mu) * rs * glv.y + blv.y,
                            xr[i][2] + (v2 - mu) * rs * glv.z + blv.z,
                            xr[i][3] + (v3 - mu) * rs * glv.w + blv.w);
        }
    }
}

extern "C" void kernel_launch(void* const* d_in, const int* in_sizes, int n_in,
                              void* d_out, int out_size, void* d_ws, size_t ws_size,
                              hipStream_t stream) {
    const float* h      = (const float*)d_in[0];
    const int*   gt_src = (const int*)d_in[1];
    const int*   gt_dst = (const int*)d_in[2];
    const int*   at_src = (const int*)d_in[3];
    const int*   at_dst = (const int*)d_in[4];
    const float* W1     = (const float*)d_in[5];
    const float* b1     = (const float*)d_in[6];
    const float* W2     = (const float*)d_in[7];
    const float* b2     = (const float*)d_in[8];
    const float* W3     = (const float*)d_in[9];
    const float* b3     = (const float*)d_in[10];
    const float* fW1    = (const float*)d_in[11];
    const float* fb1    = (const float*)d_in[12];
    const float* fW2    = (const float*)d_in[13];
    const float* fb2    = (const float*)d_in[14];
    const float* ln_g   = (const float*)d_in[15];
    const float* ln_b   = (const float*)d_in[16];

    const int E = in_sizes[1];
    const int N = in_sizes[0] / DD;
    const size_t NB = (size_t)N * DD;
    const int N2 = 2 * N;
    const int Btot = (N2 + BWIDTH - 1) >> BSH;
    const int n1 = 2 * Btot * NBLK1;

    // ---- workspace layout ----
    float* w = (float*)d_ws;
    float* Qgt = w;                              // NB f32 (25.6 MB)
    unsigned short* hb    = (unsigned short*)(Qgt + NB);   // NB bf16
    unsigned short* bufAb = hb + NB;                       // NB bf16
    unsigned short* bufBb = bufAb + NB;                    // NB bf16
    float* sm = (float*)(bufBb + NB);
    float* norms = sm;  sm += N2;
    float* indeg = sm;  sm += N2;
    float* ssum  = sm;  sm += N2;
    float* Tm    = sm;  sm += (size_t)NHEAD * DD * DH;
    float* Mt    = sm;  sm += DD * DD;
    float* cvec  = sm;  sm += NHEAD * DH + 32;
    int* ip = (int*)sm;
    int* rowptr = ip;  ip += ((N2 + 1 + 3) & ~3);
    int* csr    = ip;  ip += 2 * E;
    int* blkcnt = ip;  ip += ((n1 + 1 + 3) & ~3);
    int* scn    = ip;  ip += ((n1 + 1 + 3) & ~3);
    int* part   = ip;  ip += 256;
    // CSR-build scratch aliased over Qgt (written only later, in pass 3)
    int2* pairs = (int2*)Qgt;                    // 2E int2 = 9.6 MB
    int*  svals = (int*)(pairs + 2 * E);         // 2E int  = 4.8 MB
    float* Qat  = (float*)d_out;                 // reuse d_out; overwritten by k_tail

    // weight pre-combination
    k_wcomb <<<NHEAD, 256, 0, stream>>>(W2, W3, Tm);
    k_wcombT<<<NHEAD, 256, 0, stream>>>(W1, Tm, Mt);
    k_cvec  <<<1, 128, 0, stream>>>(b1, b2, Tm, W3, cvec);

    const int TB = 256;
    // h -> bf16
    k_h2b<<<(int)(NB / 4 + TB - 1) / TB, TB, 0, stream>>>((const float4*)h, (ushort4*)hb,
                                                          (int)(NB / 4));
    // CSR build (no global atomics)
    k_p1count<<<NBLK1, 256, 0, stream>>>(gt_src, gt_dst, at_src, at_dst, blkcnt, E, N, Btot);
    int nsb = (n1 + 1023) / 1024;
    k_scan1<<<nsb, 256, 0, stream>>>(blkcnt, scn, part, n1);
    k_scan2<<<1, 256, 0, stream>>>(part, nsb);
    k_scan3<<<(n1 + TB - 1) / TB, TB, 0, stream>>>(scn, part, n1, 4 * E);
    k_p1scatter<<<NBLK1, 256, 0, stream>>>(gt_src, gt_dst, at_src, at_dst, scn,
                                           pairs, svals, E, N, Btot);
    k_p2<<<Btot, 256, 0, stream>>>(pairs, svals, scn, rowptr, csr, indeg, norms,
                                   E, N2, Btot);

    // pull passes (bf16 gathers, R6 form): 8 nodes/block, 32 lanes/node
    const int pgrid = (N + 7) / 8;
    for (int g = 0; g < 2; ++g) {
        const int* rp = rowptr + g * N;
        const float* ns = norms + g * N;
        float* Q = g ? Qat : Qgt;
        k_pull_avg<<<pgrid, 256, 0, stream>>>((const ushort4*)hb, rp, csr, ns,
                                              (ushort4*)bufAb, N, 0);
        k_pull_avg<<<pgrid, 256, 0, stream>>>((const ushort4*)bufAb, rp, csr, ns,
                                              (ushort4*)bufBb, N, 1);
        k_pull3<<<pgrid, 256, 0, stream>>>((const ushort4*)bufBb, rp, csr, ns,
                                           (float4*)Q, ssum + g * N, N);
    }

    // fused dense tail (32 rows/block, 4x4 register tiles, swizzled LDS)
    k_tail<<<(N + 31) / 32, 256, 0, stream>>>((const float4*)Qgt, (const float4*)Qat,
                                              ssum, indeg, Mt, cvec, b3, h, ln_g, ln_b,
                                              fW1, fb1, fW2, fb2, (float*)d_out, N);
}